// Round 11
// baseline (216.796 us; speedup 1.0000x reference)
//
#include <hip/hip_runtime.h>

typedef unsigned short u16;
typedef unsigned int u32;
typedef __bf16 bf16x8 __attribute__((ext_vector_type(8)));
typedef float f32x4 __attribute__((ext_vector_type(4)));
typedef u16 u16x8 __attribute__((ext_vector_type(8)));

__device__ __forceinline__ u16 f2bf(float f) {
    __bf16 h = (__bf16)f;
    return __builtin_bit_cast(u16, h);
}
__device__ __forceinline__ float bf2f(u16 u) {
    unsigned int x = ((unsigned int)u) << 16;
    return __builtin_bit_cast(float, x);
}

union FragU { u16x8 u; bf16x8 v; };

// ---------------- workspace layout (float offsets) ----------------
constexpr size_t WB2F  = 0;        // 18432 f = 36864 u16 : frw2 bf16 [tap][och][cin]
constexpr size_t WB3F  = 18432;    // 18432 : frw3
constexpr size_t WBV2  = 36864;    // 18432 : vrw2
constexpr size_t W1T   = 55296;    // 2048 f = 4096 u16 : mw1 rows 1..64, [col][row-1]
constexpr size_t W2T   = 57344;    // 2048 : mw2 transposed [j2][j1]
constexpr size_t X1    = 59392;    // 258048 f = 4*2016*64 u16 (ch-last bf16)
constexpr size_t X2    = 317440;   // 258048
constexpr size_t FEATBF= 575488;   // 258048
constexpr size_t NVOFF = 833536;   // 28672 : [(b*7+v)*2+s][1024]
constexpr size_t CFOFF = 862208;   // 28672
constexpr size_t NOVEL = 890880;   // 14336 : [b*7+v][1024] f32
constexpr size_t Y1    = 905216;   // 458752 f = 14*1024*64 u16
constexpr size_t Y2    = 1363968;  // 458752

// ================= D1: feature conv1 (3->64) + prep slice ================
// grid (8 og, 8 pt, 5): z<4 = conv1 on image z; z==4 = weight prep (64 blocks).
__global__ __launch_bounds__(256) void conv1feat_kernel(
    const float* __restrict__ in0, const float* __restrict__ in1,
    const float* __restrict__ in2,
    const float* __restrict__ wts, const float* __restrict__ bias,
    u16* __restrict__ out,
    const float* __restrict__ frw2, const float* __restrict__ frw3,
    const float* __restrict__ vrw2,
    const float* __restrict__ mw1, const float* __restrict__ mw2,
    u16* __restrict__ wb2, u16* __restrict__ wb3, u16* __restrict__ wbv,
    u16* __restrict__ w1t, u16* __restrict__ w2t)
{
    constexpr int W = 63, NPX = 2016, H = 32;
    const int t = threadIdx.x;
    if (blockIdx.z == 4) {
        // ---- prep: weight convert/transpose (block-disjoint from conv1) ----
        const int tid = (blockIdx.y * 8 + blockIdx.x) * 256 + t;
        for (int i = tid; i < 36864; i += 16384) {
            int tap = i >> 12, och = (i >> 6) & 63, cin = i & 63;
            size_t s = (size_t)och * 576 + cin * 9 + tap;
            wb2[i] = f2bf(frw2[s]);
            wb3[i] = f2bf(frw3[s]);
            wbv[i] = f2bf(vrw2[s]);
        }
        for (int i = tid; i < 4096; i += 16384) {
            int col = i >> 6, r = i & 63;
            w1t[i] = f2bf(mw1[(1 + r) * 64 + col]);
            w2t[i] = f2bf(mw2[r * 64 + col]);
        }
        return;
    }
    const int px = blockIdx.y * 256 + t;
    const int m = blockIdx.z;
    const int og = blockIdx.x;
    if (px >= NPX) return;
    const int y = px / W, x = px - y * W;

    float acc[8];
#pragma unroll
    for (int oc = 0; oc < 8; ++oc) acc[oc] = bias[og * 8 + oc];

#pragma unroll
    for (int cin = 0; cin < 3; ++cin) {
        const float* ip = (cin == 0 ? in0 : (cin == 1 ? in1 : in2)) + (size_t)m * NPX;
        float tap[9];
#pragma unroll
        for (int dy = 0; dy < 3; ++dy) {
            int yy = y + dy - 1;
            bool ry = (yy >= 0) && (yy < H);
#pragma unroll
            for (int dx = 0; dx < 3; ++dx) {
                int xx = x + dx - 1;
                tap[dy * 3 + dx] = (ry && xx >= 0 && xx < W) ? ip[yy * W + xx] : 0.f;
            }
        }
#pragma unroll
        for (int oc = 0; oc < 8; ++oc) {
            const float* wr = wts + (size_t)(og * 8 + oc) * 27 + cin * 9;
#pragma unroll
            for (int j = 0; j < 9; ++j) acc[oc] = fmaf(tap[j], wr[j], acc[oc]);
        }
    }
    u16x8 pk;
#pragma unroll
    for (int oc = 0; oc < 8; ++oc) pk[oc] = f2bf(fmaxf(acc[oc], 0.f));
    *(u16x8*)(out + ((size_t)m * NPX + px) * 64 + og * 8) = pk;
}

// ================= convMFMA: weights direct from global bf16 ===============
template<int W, int NPX>
__global__ __launch_bounds__(256) void convmfma_kernel(
    const u16* __restrict__ in, const u16* __restrict__ wbf,
    const float* __restrict__ bias, u16* __restrict__ out)
{
    constexpr int H = 32;
    const int t = threadIdx.x;
    const int base = blockIdx.x * 64;
    const int m = blockIdx.y;
    const int w = t >> 6, lane = t & 63, q = lane >> 4, l15 = lane & 15;

    const u16* im = in + (size_t)m * NPX * 64;
    const int pxA = base + w * 16 + l15;
    const int yA = pxA / W, xA = pxA - yA * W;
    const bool pxok = (pxA < NPX);

    f32x4 acc[4];
#pragma unroll
    for (int nt = 0; nt < 4; ++nt) acc[nt] = f32x4{0.f, 0.f, 0.f, 0.f};

#pragma unroll
    for (int tap = 0; tap < 9; ++tap) {
        const int dy = tap / 3 - 1, dx = tap % 3 - 1;
        const bool valid = pxok && (yA + dy >= 0) && (yA + dy < H)
                                && (xA + dx >= 0) && (xA + dx < W);
        const u16* ap = im + (size_t)(pxA + dy * W + dx) * 64;
        FragU a0, a1;
        if (valid) {
            a0 = *(const FragU*)(ap + q * 8);
            a1 = *(const FragU*)(ap + 32 + q * 8);
        } else {
#pragma unroll
            for (int jj = 0; jj < 8; ++jj) { a0.u[jj] = 0; a1.u[jj] = 0; }
        }
#pragma unroll
        for (int nt = 0; nt < 4; ++nt) {
            const u16* bp = wbf + tap * 4096 + (nt * 16 + l15) * 64;
            FragU b0 = *(const FragU*)(bp + q * 8);
            FragU b1 = *(const FragU*)(bp + 32 + q * 8);
            acc[nt] = __builtin_amdgcn_mfma_f32_16x16x32_bf16(a0.v, b0.v, acc[nt], 0, 0, 0);
            acc[nt] = __builtin_amdgcn_mfma_f32_16x16x32_bf16(a1.v, b1.v, acc[nt], 0, 0, 0);
        }
    }

#pragma unroll
    for (int nt = 0; nt < 4; ++nt) {
        const float bb = bias[nt * 16 + l15];
#pragma unroll
        for (int e = 0; e < 4; ++e) {
            int pxs = base + w * 16 + q * 4 + e;
            if (pxs < NPX)
                out[((size_t)m * NPX + pxs) * 64 + nt * 16 + l15] =
                    f2bf(fmaxf(acc[nt][e] + bb, 0.f));
        }
    }
}

// ================= MLP, v-split: one view per block ========================
// 3584 blocks = 7 v x 4 bs x 128 n-groups. Layer-1 recomputed per view (cheap,
// 32 MFMA); per-block critical path ~1/7 of r10's, 14 blocks/CU to hide latency.
__global__ __launch_bounds__(256, 2) void mlp_mfma_kernel(
    const float* __restrict__ lf, const float* __restrict__ flow,
    const u16* __restrict__ feat,   // [bs][2016][64] bf16
    const u16* __restrict__ w1t, const u16* __restrict__ w2t,
    const float* __restrict__ w1, const float* __restrict__ b1,
    const float* __restrict__ b2,
    const float* __restrict__ w3, const float* __restrict__ b3g,
    const float* __restrict__ cw, const float* __restrict__ cbg,
    float* __restrict__ nv_out, float* __restrict__ cf_out)
{
    constexpr int SBS = 72;
    __shared__ __align__(16) float s_vec[7 * 64];
    __shared__ __align__(16) float s_flow[256];
    __shared__ __align__(16) float s_epi[256];
    __shared__ __align__(16) u16 s_base[256 * SBS];

    const int t = threadIdx.x;
    const int blk = blockIdx.x;
    const int v = blk >> 9;
    const int r9_ = blk & 511;
    const int bs = r9_ >> 7;
    const int n0 = (r9_ & 127) * 8;
    const int b = bs >> 1, s = bs & 1;
    const int w = t >> 6, lane = t & 63, q = lane >> 4, l15 = lane & 15;

    if (t < 64) {
        s_vec[t]       = b1[t];
        s_vec[64 + t]  = b2[t];
        s_vec[128 + t] = w3[t];
        s_vec[192 + t] = cw[t];
        s_vec[256 + t] = w1[t];            // row 0: flow weight
        s_vec[320 + t] = w1[65 * 64 + t];  // row 65: spatial
        s_vec[384 + t] = w1[66 * 64 + t];  // row 66: ang
    }
    {
        int nl = t >> 5, k = t & 31;
        int n = n0 + nl;
        int a = (bs * 32 + (n >> 5)) * 63 + (n & 31) + k;
        s_flow[t] = flow[a];
        s_epi[t]  = lf[a];
    }
    __syncthreads();

    const float b3s = b3g[0];
    const float cbs = cbg[0];

    FragU w1b[2][4];
#pragma unroll
    for (int ks = 0; ks < 2; ++ks)
#pragma unroll
        for (int nt = 0; nt < 4; ++nt)
            w1b[ks][nt] = *(const FragU*)(w1t + (nt * 16 + l15) * 64 + ks * 32 + q * 8);

    float w1r0pl[4], w1r65pl[4], b1pl[4];
#pragma unroll
    for (int nt = 0; nt < 4; ++nt) {
        int j1 = nt * 16 + l15;
        w1r0pl[nt]  = s_vec[256 + j1];
        w1r65pl[nt] = s_vec[320 + j1];
        b1pl[nt]    = s_vec[j1];
    }

#pragma unroll
    for (int mt = 0; mt < 4; ++mt) {
        const int rbase = w * 64 + mt * 16;
        FragU af[2];
        {
            int r = rbase + l15;
            int n = n0 + (r >> 5);
            int pos = (n >> 5) * 63 + (n & 31) + (r & 31);
            const u16* fp = feat + ((size_t)bs * 2016 + pos) * 64;
            af[0] = *(const FragU*)(fp + q * 8);
            af[1] = *(const FragU*)(fp + 32 + q * 8);
        }
        f32x4 flow4 = *(const f32x4*)(s_flow + rbase + q * 4);
#pragma unroll
        for (int nt = 0; nt < 4; ++nt) {
            f32x4 d = {0.f, 0.f, 0.f, 0.f};
            d = __builtin_amdgcn_mfma_f32_16x16x32_bf16(af[0].v, w1b[0][nt].v, d, 0, 0, 0);
            d = __builtin_amdgcn_mfma_f32_16x16x32_bf16(af[1].v, w1b[1][nt].v, d, 0, 0, 0);
#pragma unroll
            for (int e = 0; e < 4; ++e) {
                int r = rbase + q * 4 + e;
                int k = r & 31;
                float val = d[e] + flow4[e] * w1r0pl[nt]
                          + (float)(k - 16) * w1r65pl[nt] + b1pl[nt];
                s_base[r * SBS + nt * 16 + l15] = f2bf(val);
            }
        }
    }
    __syncthreads();

    FragU w2a[4][2];
#pragma unroll
    for (int mt = 0; mt < 4; ++mt)
#pragma unroll
        for (int ks = 0; ks < 2; ++ks)
            w2a[mt][ks] = *(const FragU*)(w2t + (mt * 16 + l15) * 64 + ks * 32 + q * 8);

    float w66pl[2][8];
#pragma unroll
    for (int ks = 0; ks < 2; ++ks)
#pragma unroll
        for (int jj = 0; jj < 8; ++jj)
            w66pl[ks][jj] = s_vec[384 + ks * 32 + q * 8 + jj];

    float b2pl[4][4], w3pl[4][4], cwpl[4][4];
#pragma unroll
    for (int mt = 0; mt < 4; ++mt)
#pragma unroll
        for (int e = 0; e < 4; ++e) {
            b2pl[mt][e] = s_vec[64 + mt * 16 + q * 4 + e];
            w3pl[mt][e] = s_vec[128 + mt * 16 + q * 4 + e];
            cwpl[mt][e] = s_vec[192 + mt * 16 + q * 4 + e];
        }
    float epi_pl[4];
#pragma unroll
    for (int nt = 0; nt < 4; ++nt) epi_pl[nt] = s_epi[w * 64 + nt * 16 + l15];

    // ---- single view ----
    const float ang = (s == 0) ? -(float)(v + 1) : (float)(7 - v);
    f32x4 acc[4][4];
#pragma unroll
    for (int nt = 0; nt < 4; ++nt) {
        FragU bfr[2];
#pragma unroll
        for (int ks = 0; ks < 2; ++ks) {
            const u16x8 raw = *(const u16x8*)(s_base + (w * 64 + nt * 16 + l15) * SBS + ks * 32 + q * 8);
#pragma unroll
            for (int jj = 0; jj < 8; ++jj) {
                float xv = bf2f(raw[jj]);
                float hv = fmaxf(xv + ang * w66pl[ks][jj], 0.f);
                bfr[ks].u[jj] = f2bf(hv);
            }
        }
#pragma unroll
        for (int mt = 0; mt < 4; ++mt) {
            f32x4 d = {0.f, 0.f, 0.f, 0.f};
            d = __builtin_amdgcn_mfma_f32_16x16x32_bf16(w2a[mt][0].v, bfr[0].v, d, 0, 0, 0);
            d = __builtin_amdgcn_mfma_f32_16x16x32_bf16(w2a[mt][1].v, bfr[1].v, d, 0, 0, 0);
            acc[mt][nt] = d;
        }
    }
    float wl[4], cfl[4];
#pragma unroll
    for (int nt = 0; nt < 4; ++nt) {
        float wls = 0.f, cfs = 0.f;
#pragma unroll
        for (int mt = 0; mt < 4; ++mt)
#pragma unroll
            for (int e = 0; e < 4; ++e) {
                float h2 = fmaxf(acc[mt][nt][e] + b2pl[mt][e], 0.f);
                wls += h2 * w3pl[mt][e];
                cfs += h2 * cwpl[mt][e];
            }
        wls += __shfl_xor(wls, 16); wls += __shfl_xor(wls, 32);
        cfs += __shfl_xor(cfs, 16); cfs += __shfl_xor(cfs, 32);
        wl[nt]  = wls + b3s;
        cfl[nt] = cfs;
    }
#pragma unroll
    for (int ni = 0; ni < 2; ++ni) {
        float a0 = wl[ni * 2], a1 = wl[ni * 2 + 1];
        float mx = fmaxf(a0, a1);
#pragma unroll
        for (int msk = 1; msk <= 8; msk <<= 1) mx = fmaxf(mx, __shfl_xor(mx, msk));
        float e0 = __expf(a0 - mx), e1 = __expf(a1 - mx);
        float ssum = e0 + e1;
        float nvp = e0 * epi_pl[ni * 2] + e1 * epi_pl[ni * 2 + 1];
        float cfp = cfl[ni * 2] + cfl[ni * 2 + 1];
#pragma unroll
        for (int msk = 1; msk <= 8; msk <<= 1) {
            ssum += __shfl_xor(ssum, msk);
            nvp  += __shfl_xor(nvp, msk);
            cfp  += __shfl_xor(cfp, msk);
        }
        if (lane == 0) {
            int n = n0 + w * 2 + ni;
            size_t idx = ((size_t)(b * 7 + v) * 2 + s) * 1024 + n;
            nv_out[idx] = nvp / ssum;
            cf_out[idx] = cfp * (1.f / 32.f) + cbs;
        }
    }
}

// ================= refine conv1 (3->64) with fused conf-combine ============
// grid (8 og, 4 pt, 14 m). Block stages pn rows [pt*8-1, pt*8+8] in LDS via
// the same combine arithmetic (bit-identical); og==0 writes novel for convlast.
__global__ __launch_bounds__(256) void refconv1_kernel(
    const float* __restrict__ nv, const float* __restrict__ cf,
    const float* __restrict__ pl, const float* __restrict__ pr,
    const float* __restrict__ wts, const float* __restrict__ bias,
    u16* __restrict__ out, float* __restrict__ novel)
{
    __shared__ float pn[10][32];
    const int t = threadIdx.x;
    const int og = blockIdx.x, pt = blockIdx.y, m = blockIdx.z;
    const int y0 = pt * 8;

    for (int i = t; i < 320; i += 256) {
        int ri = i >> 5, col = i & 31;
        int gy = y0 - 1 + ri;
        float vv = 0.f;
        if (gy >= 0 && gy < 32) {
            int n = gy * 32 + col;
            size_t i0 = ((size_t)m * 2) * 1024 + n;
            size_t i1 = i0 + 1024;
            float c0 = cf[i0], c1 = cf[i1];
            float mx = fmaxf(c0, c1);
            float e0 = __expf(c0 - mx), e1 = __expf(c1 - mx);
            vv = (e0 * nv[i0] + e1 * nv[i1]) / (e0 + e1);
        }
        pn[ri][col] = vv;
    }
    __syncthreads();

    const int px = y0 * 32 + t;
    const int y = px >> 5, x = px & 31;
    if (og == 0) novel[(size_t)m * 1024 + px] = pn[y - y0 + 1][x];

    float acc[8];
#pragma unroll
    for (int oc = 0; oc < 8; ++oc) acc[oc] = bias[og * 8 + oc];

    // cin 0: pn from LDS
    {
        float tap[9];
#pragma unroll
        for (int dy = 0; dy < 3; ++dy) {
#pragma unroll
            for (int dx = 0; dx < 3; ++dx) {
                int gx = x + dx - 1;
                tap[dy * 3 + dx] = (gx >= 0 && gx < 32) ? pn[y - y0 + dy][gx] : 0.f;
            }
        }
#pragma unroll
        for (int oc = 0; oc < 8; ++oc) {
            const float* wr = wts + (size_t)(og * 8 + oc) * 27;
#pragma unroll
            for (int j = 0; j < 9; ++j) acc[oc] = fmaf(tap[j], wr[j], acc[oc]);
        }
    }
    // cin 1,2: pl/pr from global
#pragma unroll
    for (int cin = 1; cin < 3; ++cin) {
        const float* ip = (cin == 1 ? pl : pr) + (size_t)m * 1024;
        float tap[9];
#pragma unroll
        for (int dy = 0; dy < 3; ++dy) {
            int yy = y + dy - 1;
            bool ry = (yy >= 0) && (yy < 32);
#pragma unroll
            for (int dx = 0; dx < 3; ++dx) {
                int xx = x + dx - 1;
                tap[dy * 3 + dx] = (ry && xx >= 0 && xx < 32) ? ip[yy * 32 + xx] : 0.f;
            }
        }
#pragma unroll
        for (int oc = 0; oc < 8; ++oc) {
            const float* wr = wts + (size_t)(og * 8 + oc) * 27 + cin * 9;
#pragma unroll
            for (int j = 0; j < 9; ++j) acc[oc] = fmaf(tap[j], wr[j], acc[oc]);
        }
    }
    u16x8 pk;
#pragma unroll
    for (int oc = 0; oc < 8; ++oc) pk[oc] = f2bf(fmaxf(acc[oc], 0.f));
    *(u16x8*)(out + ((size_t)m * 1024 + px) * 64 + og * 8) = pk;
}

// ================= convlast: 64 -> 1 + bias + residual =====================
__global__ __launch_bounds__(256) void convlast_kernel(
    const u16* __restrict__ in,     // [14][1024][64] bf16 ch-last
    const float* __restrict__ wts,  // [64][9]
    const float* __restrict__ bias, // [1]
    const float* __restrict__ resid,// [14][1024] f32
    float* __restrict__ out)        // [14][1024] f32
{
    __shared__ float sw3[576];
    const int t = threadIdx.x;
    for (int i = t; i < 576; i += 256) sw3[i] = wts[i];
    __syncthreads();

    const int tid = blockIdx.x * 256 + t;
    const int m = tid >> 10, p = tid & 1023;
    const int y = p >> 5, x = p & 31;
    float a = bias[0] + resid[tid];
    const u16* im = in + ((size_t)m * 1024 + p) * 64;
#pragma unroll
    for (int dy = 0; dy < 3; ++dy) {
        int yy = y + dy - 1;
        if (yy < 0 || yy >= 32) continue;
#pragma unroll
        for (int dx = 0; dx < 3; ++dx) {
            int xx = x + dx - 1;
            if (xx < 0 || xx >= 32) continue;
            const u16* ip = im + (size_t)((dy - 1) * 32 + (dx - 1)) * 64;
            const int tap = dy * 3 + dx;
#pragma unroll
            for (int cg = 0; cg < 8; ++cg) {
                u16x8 raw = *(const u16x8*)(ip + cg * 8);
#pragma unroll
                for (int e = 0; e < 8; ++e)
                    a = fmaf(bf2f(raw[e]), sw3[(cg * 8 + e) * 9 + tap], a);
            }
        }
    }
    out[tid] = a;
}

// ---------------- launch ----------------
extern "C" void kernel_launch(void* const* d_in, const int* in_sizes, int n_in,
                              void* d_out, int out_size, void* d_ws, size_t ws_size,
                              hipStream_t stream) {
    const float* lf   = (const float*)d_in[0];
    const float* flow = (const float*)d_in[1];
    const float* wp   = (const float*)d_in[2];
    const float* pl   = (const float*)d_in[3];
    const float* pr   = (const float*)d_in[4];
    float* ws = (float*)d_ws;

    // D1: feature conv1 + weight prep (block-disjoint)
    conv1feat_kernel<<<dim3(8, 8, 5), 256, 0, stream>>>(
        flow, lf, wp, (const float*)d_in[5], (const float*)d_in[6],
        (u16*)(ws + X1),
        (const float*)d_in[7], (const float*)d_in[9], (const float*)d_in[21],
        (const float*)d_in[11], (const float*)d_in[13],
        (u16*)(ws + WB2F), (u16*)(ws + WB3F), (u16*)(ws + WBV2),
        (u16*)(ws + W1T), (u16*)(ws + W2T));

    convmfma_kernel<63, 2016><<<dim3(32, 4), 256, 0, stream>>>(
        (const u16*)(ws + X1), (const u16*)(ws + WB2F), (const float*)d_in[8],
        (u16*)(ws + X2));
    convmfma_kernel<63, 2016><<<dim3(32, 4), 256, 0, stream>>>(
        (const u16*)(ws + X2), (const u16*)(ws + WB3F), (const float*)d_in[10],
        (u16*)(ws + FEATBF));

    // MLP, one view per block
    mlp_mfma_kernel<<<3584, 256, 0, stream>>>(
        lf, flow, (const u16*)(ws + FEATBF),
        (const u16*)(ws + W1T), (const u16*)(ws + W2T),
        (const float*)d_in[11], (const float*)d_in[12],
        (const float*)d_in[14],
        (const float*)d_in[15], (const float*)d_in[16],
        (const float*)d_in[17], (const float*)d_in[18],
        ws + NVOFF, ws + CFOFF);

    // refinement: conv1 + fused combine (og0 writes novel)
    refconv1_kernel<<<dim3(8, 4, 14), 256, 0, stream>>>(
        ws + NVOFF, ws + CFOFF, pl, pr,
        (const float*)d_in[19], (const float*)d_in[20],
        (u16*)(ws + Y1), ws + NOVEL);
    convmfma_kernel<32, 1024><<<dim3(16, 14), 256, 0, stream>>>(
        (const u16*)(ws + Y1), (const u16*)(ws + WBV2), (const float*)d_in[22],
        (u16*)(ws + Y2));
    convlast_kernel<<<56, 256, 0, stream>>>(
        (const u16*)(ws + Y2), (const float*)d_in[23], (const float*)d_in[24],
        ws + NOVEL, (float*)d_out);
}

// Round 13
// 203.719 us; speedup vs baseline: 1.0642x; 1.0642x over previous
//
#include <hip/hip_runtime.h>

typedef unsigned short u16;
typedef unsigned int u32;
typedef __bf16 bf16x8 __attribute__((ext_vector_type(8)));
typedef float f32x4 __attribute__((ext_vector_type(4)));
typedef u16 u16x8 __attribute__((ext_vector_type(8)));

__device__ __forceinline__ u16 f2bf(float f) {
    __bf16 h = (__bf16)f;
    return __builtin_bit_cast(u16, h);
}
__device__ __forceinline__ float bf2f(u16 u) {
    unsigned int x = ((unsigned int)u) << 16;
    return __builtin_bit_cast(float, x);
}

union FragU { u16x8 u; bf16x8 v; };

// ---------------- workspace layout (float offsets) ----------------
constexpr size_t WB2F  = 0;        // 18432 f = 36864 u16 : frw2 bf16 [tap][och][cin]
constexpr size_t WB3F  = 18432;    // 18432 : frw3
constexpr size_t WBV2  = 36864;    // 18432 : vrw2
constexpr size_t W1T   = 55296;    // 2048 f = 4096 u16 : mw1 rows 1..64, [col][row-1]
constexpr size_t W2T   = 57344;    // 2048 : mw2 transposed [j2][j1]
constexpr size_t X1    = 59392;    // 258048 f = 4*2016*64 u16 (ch-last bf16)
constexpr size_t X2    = 317440;   // 258048
constexpr size_t FEATBF= 575488;   // 258048
constexpr size_t BASEG = 833536;   // 4194304 f = 4*1024*32*64 u16 (r12 bug: was 131072 -> aliased nv/cf)
constexpr size_t NVOFF = 5027840;  // 28672 : [(b*7+v)*2+s][1024]
constexpr size_t CFOFF = 5056512;  // 28672
constexpr size_t NOVEL = 5085184;  // 14336 : [b*7+v][1024] f32
constexpr size_t Y1    = 5099520;  // 458752 f = 14*1024*64 u16
constexpr size_t Y2    = 5558272;  // 458752
// total 6017024 f = 24.1 MB

// ================= D1: feature conv1 (3->64) + prep slice ================
__global__ __launch_bounds__(256) void conv1feat_kernel(
    const float* __restrict__ in0, const float* __restrict__ in1,
    const float* __restrict__ in2,
    const float* __restrict__ wts, const float* __restrict__ bias,
    u16* __restrict__ out,
    const float* __restrict__ frw2, const float* __restrict__ frw3,
    const float* __restrict__ vrw2,
    const float* __restrict__ mw1, const float* __restrict__ mw2,
    u16* __restrict__ wb2, u16* __restrict__ wb3, u16* __restrict__ wbv,
    u16* __restrict__ w1t, u16* __restrict__ w2t)
{
    constexpr int W = 63, NPX = 2016, H = 32;
    const int t = threadIdx.x;
    if (blockIdx.z == 4) {
        const int tid = (blockIdx.y * 8 + blockIdx.x) * 256 + t;
        for (int i = tid; i < 36864; i += 16384) {
            int tap = i >> 12, och = (i >> 6) & 63, cin = i & 63;
            size_t s = (size_t)och * 576 + cin * 9 + tap;
            wb2[i] = f2bf(frw2[s]);
            wb3[i] = f2bf(frw3[s]);
            wbv[i] = f2bf(vrw2[s]);
        }
        for (int i = tid; i < 4096; i += 16384) {
            int col = i >> 6, r = i & 63;
            w1t[i] = f2bf(mw1[(1 + r) * 64 + col]);
            w2t[i] = f2bf(mw2[r * 64 + col]);
        }
        return;
    }
    const int px = blockIdx.y * 256 + t;
    const int m = blockIdx.z;
    const int og = blockIdx.x;
    if (px >= NPX) return;
    const int y = px / W, x = px - y * W;

    float acc[8];
#pragma unroll
    for (int oc = 0; oc < 8; ++oc) acc[oc] = bias[og * 8 + oc];

#pragma unroll
    for (int cin = 0; cin < 3; ++cin) {
        const float* ip = (cin == 0 ? in0 : (cin == 1 ? in1 : in2)) + (size_t)m * NPX;
        float tap[9];
#pragma unroll
        for (int dy = 0; dy < 3; ++dy) {
            int yy = y + dy - 1;
            bool ry = (yy >= 0) && (yy < H);
#pragma unroll
            for (int dx = 0; dx < 3; ++dx) {
                int xx = x + dx - 1;
                tap[dy * 3 + dx] = (ry && xx >= 0 && xx < W) ? ip[yy * W + xx] : 0.f;
            }
        }
#pragma unroll
        for (int oc = 0; oc < 8; ++oc) {
            const float* wr = wts + (size_t)(og * 8 + oc) * 27 + cin * 9;
#pragma unroll
            for (int j = 0; j < 9; ++j) acc[oc] = fmaf(tap[j], wr[j], acc[oc]);
        }
    }
    u16x8 pk;
#pragma unroll
    for (int oc = 0; oc < 8; ++oc) pk[oc] = f2bf(fmaxf(acc[oc], 0.f));
    *(u16x8*)(out + ((size_t)m * NPX + px) * 64 + og * 8) = pk;
}

// ================= convMFMA, och-split OCHS=2 ==============================
template<int W, int NPX>
__global__ __launch_bounds__(256) void convmfma_kernel(
    const u16* __restrict__ in, const u16* __restrict__ wbf,
    const float* __restrict__ bias, u16* __restrict__ out)
{
    constexpr int H = 32;
    const int t = threadIdx.x;
    const int base = blockIdx.x * 64;
    const int ochb = blockIdx.y * 32;
    const int m = blockIdx.z;
    const int w = t >> 6, lane = t & 63, q = lane >> 4, l15 = lane & 15;

    const u16* im = in + (size_t)m * NPX * 64;
    const int pxA = base + w * 16 + l15;
    const int yA = pxA / W, xA = pxA - yA * W;
    const bool pxok = (pxA < NPX);

    f32x4 acc[2];
#pragma unroll
    for (int nt = 0; nt < 2; ++nt) acc[nt] = f32x4{0.f, 0.f, 0.f, 0.f};

#pragma unroll
    for (int tap = 0; tap < 9; ++tap) {
        const int dy = tap / 3 - 1, dx = tap % 3 - 1;
        const bool valid = pxok && (yA + dy >= 0) && (yA + dy < H)
                                && (xA + dx >= 0) && (xA + dx < W);
        const u16* ap = im + (size_t)(pxA + dy * W + dx) * 64;
        FragU a0, a1;
        if (valid) {
            a0 = *(const FragU*)(ap + q * 8);
            a1 = *(const FragU*)(ap + 32 + q * 8);
        } else {
#pragma unroll
            for (int jj = 0; jj < 8; ++jj) { a0.u[jj] = 0; a1.u[jj] = 0; }
        }
#pragma unroll
        for (int nt = 0; nt < 2; ++nt) {
            const u16* bp = wbf + tap * 4096 + (ochb + nt * 16 + l15) * 64;
            FragU b0 = *(const FragU*)(bp + q * 8);
            FragU b1 = *(const FragU*)(bp + 32 + q * 8);
            acc[nt] = __builtin_amdgcn_mfma_f32_16x16x32_bf16(a0.v, b0.v, acc[nt], 0, 0, 0);
            acc[nt] = __builtin_amdgcn_mfma_f32_16x16x32_bf16(a1.v, b1.v, acc[nt], 0, 0, 0);
        }
    }

#pragma unroll
    for (int nt = 0; nt < 2; ++nt) {
        const float bb = bias[ochb + nt * 16 + l15];
#pragma unroll
        for (int e = 0; e < 4; ++e) {
            int pxs = base + w * 16 + q * 4 + e;
            if (pxs < NPX)
                out[((size_t)m * NPX + pxs) * 64 + ochb + nt * 16 + l15] =
                    f2bf(fmaxf(acc[nt][e] + bb, 0.f));
        }
    }
}

// ================= MLP stage A: layer-1 base -> global bf16 ================
__global__ __launch_bounds__(256, 2) void mlp_base_kernel(
    const float* __restrict__ flow,
    const u16* __restrict__ feat,   // [bs][2016][64] bf16
    const u16* __restrict__ w1t,
    const float* __restrict__ w1, const float* __restrict__ b1,
    u16* __restrict__ baseg)
{
    __shared__ __align__(16) float s_vec[3 * 64];  // b1, w1r0, w1r65
    __shared__ __align__(16) float s_flow[256];

    const int t = threadIdx.x;
    const int blk = blockIdx.x;
    const int bs = blk >> 7;
    const int n0 = (blk & 127) * 8;
    const int w = t >> 6, lane = t & 63, q = lane >> 4, l15 = lane & 15;

    if (t < 64) {
        s_vec[t]       = b1[t];
        s_vec[64 + t]  = w1[t];            // row 0: flow weight
        s_vec[128 + t] = w1[65 * 64 + t];  // row 65: spatial
    }
    {
        int nl = t >> 5, k = t & 31;
        int n = n0 + nl;
        int a = (bs * 32 + (n >> 5)) * 63 + (n & 31) + k;
        s_flow[t] = flow[a];
    }
    __syncthreads();

    FragU w1b[2][4];
#pragma unroll
    for (int ks = 0; ks < 2; ++ks)
#pragma unroll
        for (int nt = 0; nt < 4; ++nt)
            w1b[ks][nt] = *(const FragU*)(w1t + (nt * 16 + l15) * 64 + ks * 32 + q * 8);

    float w1r0pl[4], w1r65pl[4], b1pl[4];
#pragma unroll
    for (int nt = 0; nt < 4; ++nt) {
        int j1 = nt * 16 + l15;
        b1pl[nt]    = s_vec[j1];
        w1r0pl[nt]  = s_vec[64 + j1];
        w1r65pl[nt] = s_vec[128 + j1];
    }

#pragma unroll
    for (int mt = 0; mt < 4; ++mt) {
        const int rbase = w * 64 + mt * 16;
        FragU af[2];
        {
            int r = rbase + l15;
            int n = n0 + (r >> 5);
            int pos = (n >> 5) * 63 + (n & 31) + (r & 31);
            const u16* fp = feat + ((size_t)bs * 2016 + pos) * 64;
            af[0] = *(const FragU*)(fp + q * 8);
            af[1] = *(const FragU*)(fp + 32 + q * 8);
        }
        f32x4 flow4 = *(const f32x4*)(s_flow + rbase + q * 4);
#pragma unroll
        for (int nt = 0; nt < 4; ++nt) {
            f32x4 d = {0.f, 0.f, 0.f, 0.f};
            d = __builtin_amdgcn_mfma_f32_16x16x32_bf16(af[0].v, w1b[0][nt].v, d, 0, 0, 0);
            d = __builtin_amdgcn_mfma_f32_16x16x32_bf16(af[1].v, w1b[1][nt].v, d, 0, 0, 0);
#pragma unroll
            for (int e = 0; e < 4; ++e) {
                int r = rbase + q * 4 + e;
                int k = r & 31;
                int n = n0 + (r >> 5);
                float val = d[e] + flow4[e] * w1r0pl[nt]
                          + (float)(k - 16) * w1r65pl[nt] + b1pl[nt];
                baseg[(((size_t)bs * 1024 + n) * 32 + k) * 64 + nt * 16 + l15] = f2bf(val);
            }
        }
    }
}

// ================= MLP stage B: per-view L2/L3 + softmax + epi ============
__global__ __launch_bounds__(256, 2) void mlp_views_kernel(
    const float* __restrict__ lf,
    const u16* __restrict__ baseg,
    const u16* __restrict__ w2t,
    const float* __restrict__ w1, const float* __restrict__ b2,
    const float* __restrict__ w3, const float* __restrict__ b3g,
    const float* __restrict__ cw, const float* __restrict__ cbg,
    float* __restrict__ nv_out, float* __restrict__ cf_out)
{
    __shared__ __align__(16) float s_vec[4 * 64];  // b2, w3, cw, w66
    __shared__ __align__(16) float s_epi[256];

    const int t = threadIdx.x;
    const int blk = blockIdx.x;
    const int v = blk >> 9;
    const int r9_ = blk & 511;
    const int bs = r9_ >> 7;
    const int n0 = (r9_ & 127) * 8;
    const int b = bs >> 1, s = bs & 1;
    const int w = t >> 6, lane = t & 63, q = lane >> 4, l15 = lane & 15;

    if (t < 64) {
        s_vec[t]       = b2[t];
        s_vec[64 + t]  = w3[t];
        s_vec[128 + t] = cw[t];
        s_vec[192 + t] = w1[66 * 64 + t];  // row 66: ang
    }
    {
        int nl = t >> 5, k = t & 31;
        int n = n0 + nl;
        int a = (bs * 32 + (n >> 5)) * 63 + (n & 31) + k;
        s_epi[t] = lf[a];
    }
    __syncthreads();

    const float b3s = b3g[0];
    const float cbs = cbg[0];

    FragU w2a[4][2];
#pragma unroll
    for (int mt = 0; mt < 4; ++mt)
#pragma unroll
        for (int ks = 0; ks < 2; ++ks)
            w2a[mt][ks] = *(const FragU*)(w2t + (mt * 16 + l15) * 64 + ks * 32 + q * 8);

    float w66pl[2][8];
#pragma unroll
    for (int ks = 0; ks < 2; ++ks)
#pragma unroll
        for (int jj = 0; jj < 8; ++jj)
            w66pl[ks][jj] = s_vec[192 + ks * 32 + q * 8 + jj];

    float b2pl[4][4], w3pl[4][4], cwpl[4][4];
#pragma unroll
    for (int mt = 0; mt < 4; ++mt)
#pragma unroll
        for (int e = 0; e < 4; ++e) {
            b2pl[mt][e] = s_vec[mt * 16 + q * 4 + e];
            w3pl[mt][e] = s_vec[64 + mt * 16 + q * 4 + e];
            cwpl[mt][e] = s_vec[128 + mt * 16 + q * 4 + e];
        }
    float epi_pl[4];
#pragma unroll
    for (int nt = 0; nt < 4; ++nt) epi_pl[nt] = s_epi[w * 64 + nt * 16 + l15];

    const float ang = (s == 0) ? -(float)(v + 1) : (float)(7 - v);
    f32x4 acc[4][4];
#pragma unroll
    for (int nt = 0; nt < 4; ++nt) {
        const int row = w * 64 + nt * 16 + l15;
        const int n = n0 + (row >> 5), k = row & 31;
        const u16* bp = baseg + (((size_t)bs * 1024 + n) * 32 + k) * 64;
        FragU bfr[2];
#pragma unroll
        for (int ks = 0; ks < 2; ++ks) {
            const u16x8 raw = *(const u16x8*)(bp + ks * 32 + q * 8);
#pragma unroll
            for (int jj = 0; jj < 8; ++jj) {
                float xv = bf2f(raw[jj]);
                float hv = fmaxf(xv + ang * w66pl[ks][jj], 0.f);
                bfr[ks].u[jj] = f2bf(hv);
            }
        }
#pragma unroll
        for (int mt = 0; mt < 4; ++mt) {
            f32x4 d = {0.f, 0.f, 0.f, 0.f};
            d = __builtin_amdgcn_mfma_f32_16x16x32_bf16(w2a[mt][0].v, bfr[0].v, d, 0, 0, 0);
            d = __builtin_amdgcn_mfma_f32_16x16x32_bf16(w2a[mt][1].v, bfr[1].v, d, 0, 0, 0);
            acc[mt][nt] = d;
        }
    }
    float wl[4], cfl[4];
#pragma unroll
    for (int nt = 0; nt < 4; ++nt) {
        float wls = 0.f, cfs = 0.f;
#pragma unroll
        for (int mt = 0; mt < 4; ++mt)
#pragma unroll
            for (int e = 0; e < 4; ++e) {
                float h2 = fmaxf(acc[mt][nt][e] + b2pl[mt][e], 0.f);
                wls += h2 * w3pl[mt][e];
                cfs += h2 * cwpl[mt][e];
            }
        wls += __shfl_xor(wls, 16); wls += __shfl_xor(wls, 32);
        cfs += __shfl_xor(cfs, 16); cfs += __shfl_xor(cfs, 32);
        wl[nt]  = wls + b3s;
        cfl[nt] = cfs;
    }
#pragma unroll
    for (int ni = 0; ni < 2; ++ni) {
        float a0 = wl[ni * 2], a1 = wl[ni * 2 + 1];
        float mx = fmaxf(a0, a1);
#pragma unroll
        for (int msk = 1; msk <= 8; msk <<= 1) mx = fmaxf(mx, __shfl_xor(mx, msk));
        float e0 = __expf(a0 - mx), e1 = __expf(a1 - mx);
        float ssum = e0 + e1;
        float nvp = e0 * epi_pl[ni * 2] + e1 * epi_pl[ni * 2 + 1];
        float cfp = cfl[ni * 2] + cfl[ni * 2 + 1];
#pragma unroll
        for (int msk = 1; msk <= 8; msk <<= 1) {
            ssum += __shfl_xor(ssum, msk);
            nvp  += __shfl_xor(nvp, msk);
            cfp  += __shfl_xor(cfp, msk);
        }
        if (lane == 0) {
            int n = n0 + w * 2 + ni;
            size_t idx = ((size_t)(b * 7 + v) * 2 + s) * 1024 + n;
            nv_out[idx] = nvp / ssum;
            cf_out[idx] = cfp * (1.f / 32.f) + cbs;
        }
    }
}

// ================= refine conv1 (3->64) with fused conf-combine ============
__global__ __launch_bounds__(256) void refconv1_kernel(
    const float* __restrict__ nv, const float* __restrict__ cf,
    const float* __restrict__ pl, const float* __restrict__ pr,
    const float* __restrict__ wts, const float* __restrict__ bias,
    u16* __restrict__ out, float* __restrict__ novel)
{
    __shared__ float pn[10][32];
    const int t = threadIdx.x;
    const int og = blockIdx.x, pt = blockIdx.y, m = blockIdx.z;
    const int y0 = pt * 8;

    for (int i = t; i < 320; i += 256) {
        int ri = i >> 5, col = i & 31;
        int gy = y0 - 1 + ri;
        float vv = 0.f;
        if (gy >= 0 && gy < 32) {
            int n = gy * 32 + col;
            size_t i0 = ((size_t)m * 2) * 1024 + n;
            size_t i1 = i0 + 1024;
            float c0 = cf[i0], c1 = cf[i1];
            float mx = fmaxf(c0, c1);
            float e0 = __expf(c0 - mx), e1 = __expf(c1 - mx);
            vv = (e0 * nv[i0] + e1 * nv[i1]) / (e0 + e1);
        }
        pn[ri][col] = vv;
    }
    __syncthreads();

    const int px = y0 * 32 + t;
    const int y = px >> 5, x = px & 31;
    if (og == 0) novel[(size_t)m * 1024 + px] = pn[y - y0 + 1][x];

    float acc[8];
#pragma unroll
    for (int oc = 0; oc < 8; ++oc) acc[oc] = bias[og * 8 + oc];

    {
        float tap[9];
#pragma unroll
        for (int dy = 0; dy < 3; ++dy) {
#pragma unroll
            for (int dx = 0; dx < 3; ++dx) {
                int gx = x + dx - 1;
                tap[dy * 3 + dx] = (gx >= 0 && gx < 32) ? pn[y - y0 + dy][gx] : 0.f;
            }
        }
#pragma unroll
        for (int oc = 0; oc < 8; ++oc) {
            const float* wr = wts + (size_t)(og * 8 + oc) * 27;
#pragma unroll
            for (int j = 0; j < 9; ++j) acc[oc] = fmaf(tap[j], wr[j], acc[oc]);
        }
    }
#pragma unroll
    for (int cin = 1; cin < 3; ++cin) {
        const float* ip = (cin == 1 ? pl : pr) + (size_t)m * 1024;
        float tap[9];
#pragma unroll
        for (int dy = 0; dy < 3; ++dy) {
            int yy = y + dy - 1;
            bool ry = (yy >= 0) && (yy < 32);
#pragma unroll
            for (int dx = 0; dx < 3; ++dx) {
                int xx = x + dx - 1;
                tap[dy * 3 + dx] = (ry && xx >= 0 && xx < 32) ? ip[yy * 32 + xx] : 0.f;
            }
        }
#pragma unroll
        for (int oc = 0; oc < 8; ++oc) {
            const float* wr = wts + (size_t)(og * 8 + oc) * 27 + cin * 9;
#pragma unroll
            for (int j = 0; j < 9; ++j) acc[oc] = fmaf(tap[j], wr[j], acc[oc]);
        }
    }
    u16x8 pk;
#pragma unroll
    for (int oc = 0; oc < 8; ++oc) pk[oc] = f2bf(fmaxf(acc[oc], 0.f));
    *(u16x8*)(out + ((size_t)m * 1024 + px) * 64 + og * 8) = pk;
}

// ================= convlast: 64 -> 1 + bias + residual =====================
__global__ __launch_bounds__(256) void convlast_kernel(
    const u16* __restrict__ in, const float* __restrict__ wts,
    const float* __restrict__ bias, const float* __restrict__ resid,
    float* __restrict__ out)
{
    __shared__ float sw3[576];
    const int t = threadIdx.x;
    for (int i = t; i < 576; i += 256) sw3[i] = wts[i];
    __syncthreads();

    const int tid = blockIdx.x * 256 + t;
    const int m = tid >> 10, p = tid & 1023;
    const int y = p >> 5, x = p & 31;
    float a = bias[0] + resid[tid];
    const u16* im = in + ((size_t)m * 1024 + p) * 64;
#pragma unroll
    for (int dy = 0; dy < 3; ++dy) {
        int yy = y + dy - 1;
        if (yy < 0 || yy >= 32) continue;
#pragma unroll
        for (int dx = 0; dx < 3; ++dx) {
            int xx = x + dx - 1;
            if (xx < 0 || xx >= 32) continue;
            const u16* ip = im + (size_t)((dy - 1) * 32 + (dx - 1)) * 64;
            const int tap = dy * 3 + dx;
#pragma unroll
            for (int cg = 0; cg < 8; ++cg) {
                u16x8 raw = *(const u16x8*)(ip + cg * 8);
#pragma unroll
                for (int e = 0; e < 8; ++e)
                    a = fmaf(bf2f(raw[e]), sw3[(cg * 8 + e) * 9 + tap], a);
            }
        }
    }
    out[tid] = a;
}

// ---------------- launch ----------------
extern "C" void kernel_launch(void* const* d_in, const int* in_sizes, int n_in,
                              void* d_out, int out_size, void* d_ws, size_t ws_size,
                              hipStream_t stream) {
    const float* lf   = (const float*)d_in[0];
    const float* flow = (const float*)d_in[1];
    const float* wp   = (const float*)d_in[2];
    const float* pl   = (const float*)d_in[3];
    const float* pr   = (const float*)d_in[4];
    float* ws = (float*)d_ws;

    conv1feat_kernel<<<dim3(8, 8, 5), 256, 0, stream>>>(
        flow, lf, wp, (const float*)d_in[5], (const float*)d_in[6],
        (u16*)(ws + X1),
        (const float*)d_in[7], (const float*)d_in[9], (const float*)d_in[21],
        (const float*)d_in[11], (const float*)d_in[13],
        (u16*)(ws + WB2F), (u16*)(ws + WB3F), (u16*)(ws + WBV2),
        (u16*)(ws + W1T), (u16*)(ws + W2T));

    convmfma_kernel<63, 2016><<<dim3(32, 2, 4), 256, 0, stream>>>(
        (const u16*)(ws + X1), (const u16*)(ws + WB2F), (const float*)d_in[8],
        (u16*)(ws + X2));
    convmfma_kernel<63, 2016><<<dim3(32, 2, 4), 256, 0, stream>>>(
        (const u16*)(ws + X2), (const u16*)(ws + WB3F), (const float*)d_in[10],
        (u16*)(ws + FEATBF));

    mlp_base_kernel<<<512, 256, 0, stream>>>(
        flow, (const u16*)(ws + FEATBF), (const u16*)(ws + W1T),
        (const float*)d_in[11], (const float*)d_in[12],
        (u16*)(ws + BASEG));

    mlp_views_kernel<<<3584, 256, 0, stream>>>(
        lf, (const u16*)(ws + BASEG), (const u16*)(ws + W2T),
        (const float*)d_in[11], (const float*)d_in[14],
        (const float*)d_in[15], (const float*)d_in[16],
        (const float*)d_in[17], (const float*)d_in[18],
        ws + NVOFF, ws + CFOFF);

    refconv1_kernel<<<dim3(8, 4, 14), 256, 0, stream>>>(
        ws + NVOFF, ws + CFOFF, pl, pr,
        (const float*)d_in[19], (const float*)d_in[20],
        (u16*)(ws + Y1), ws + NOVEL);
    convmfma_kernel<32, 1024><<<dim3(16, 2, 14), 256, 0, stream>>>(
        (const u16*)(ws + Y1), (const u16*)(ws + WBV2), (const float*)d_in[22],
        (u16*)(ws + Y2));
    convlast_kernel<<<56, 256, 0, stream>>>(
        (const u16*)(ws + Y2), (const float*)d_in[23], (const float*)d_in[24],
        ws + NOVEL, (float*)d_out);
}

// Round 14
// 186.672 us; speedup vs baseline: 1.1614x; 1.0913x over previous
//
#include <hip/hip_runtime.h>

typedef unsigned short u16;
typedef unsigned int u32;
typedef __bf16 bf16x8 __attribute__((ext_vector_type(8)));
typedef float f32x4 __attribute__((ext_vector_type(4)));
typedef u16 u16x8 __attribute__((ext_vector_type(8)));

__device__ __forceinline__ u16 f2bf(float f) {
    __bf16 h = (__bf16)f;
    return __builtin_bit_cast(u16, h);
}
__device__ __forceinline__ float bf2f(u16 u) {
    unsigned int x = ((unsigned int)u) << 16;
    return __builtin_bit_cast(float, x);
}

union FragU { u16x8 u; bf16x8 v; };

// ---------------- workspace layout (float offsets) ----------------
constexpr size_t WB2F  = 0;        // 18432 f = 36864 u16 : frw2 bf16 [tap][och][cin]
constexpr size_t WB3F  = 18432;    // 18432 : frw3
constexpr size_t WBV2  = 36864;    // 18432 : vrw2
constexpr size_t W1T   = 55296;    // 2048 f = 4096 u16 : mw1 rows 1..64, [col][row-1]
constexpr size_t W2T   = 57344;    // 2048 : mw2 transposed [j2][j1]
constexpr size_t X1    = 59392;    // 258048 f = 4*2016*64 u16 (ch-last bf16)
constexpr size_t X2    = 317440;   // 258048
constexpr size_t FEATBF= 575488;   // 258048
constexpr size_t NVOFF = 833536;   // 28672 : [(b*7+v)*2+s][1024]
constexpr size_t CFOFF = 862208;   // 28672
constexpr size_t NOVEL = 890880;   // 14336 : [b*7+v][1024] f32
constexpr size_t Y1    = 905216;   // 458752 f = 14*1024*64 u16
constexpr size_t Y2    = 1363968;  // 458752

// ================= D1: feature conv1 (3->64) + prep slice (r13-verified) ===
__global__ __launch_bounds__(256) void conv1feat_kernel(
    const float* __restrict__ in0, const float* __restrict__ in1,
    const float* __restrict__ in2,
    const float* __restrict__ wts, const float* __restrict__ bias,
    u16* __restrict__ out,
    const float* __restrict__ frw2, const float* __restrict__ frw3,
    const float* __restrict__ vrw2,
    const float* __restrict__ mw1, const float* __restrict__ mw2,
    u16* __restrict__ wb2, u16* __restrict__ wb3, u16* __restrict__ wbv,
    u16* __restrict__ w1t, u16* __restrict__ w2t)
{
    constexpr int W = 63, NPX = 2016, H = 32;
    const int t = threadIdx.x;
    if (blockIdx.z == 4) {
        const int tid = (blockIdx.y * 8 + blockIdx.x) * 256 + t;
        for (int i = tid; i < 36864; i += 16384) {
            int tap = i >> 12, och = (i >> 6) & 63, cin = i & 63;
            size_t s = (size_t)och * 576 + cin * 9 + tap;
            wb2[i] = f2bf(frw2[s]);
            wb3[i] = f2bf(frw3[s]);
            wbv[i] = f2bf(vrw2[s]);
        }
        for (int i = tid; i < 4096; i += 16384) {
            int col = i >> 6, r = i & 63;
            w1t[i] = f2bf(mw1[(1 + r) * 64 + col]);
            w2t[i] = f2bf(mw2[r * 64 + col]);
        }
        return;
    }
    const int px = blockIdx.y * 256 + t;
    const int m = blockIdx.z;
    const int og = blockIdx.x;
    if (px >= NPX) return;
    const int y = px / W, x = px - y * W;

    float acc[8];
#pragma unroll
    for (int oc = 0; oc < 8; ++oc) acc[oc] = bias[og * 8 + oc];

#pragma unroll
    for (int cin = 0; cin < 3; ++cin) {
        const float* ip = (cin == 0 ? in0 : (cin == 1 ? in1 : in2)) + (size_t)m * NPX;
        float tap[9];
#pragma unroll
        for (int dy = 0; dy < 3; ++dy) {
            int yy = y + dy - 1;
            bool ry = (yy >= 0) && (yy < H);
#pragma unroll
            for (int dx = 0; dx < 3; ++dx) {
                int xx = x + dx - 1;
                tap[dy * 3 + dx] = (ry && xx >= 0 && xx < W) ? ip[yy * W + xx] : 0.f;
            }
        }
#pragma unroll
        for (int oc = 0; oc < 8; ++oc) {
            const float* wr = wts + (size_t)(og * 8 + oc) * 27 + cin * 9;
#pragma unroll
            for (int j = 0; j < 9; ++j) acc[oc] = fmaf(tap[j], wr[j], acc[oc]);
        }
    }
    u16x8 pk;
#pragma unroll
    for (int oc = 0; oc < 8; ++oc) pk[oc] = f2bf(fmaxf(acc[oc], 0.f));
    *(u16x8*)(out + ((size_t)m * NPX + px) * 64 + og * 8) = pk;
}

// ================= convMFMA, och-split (r13-verified) ======================
template<int W, int NPX>
__global__ __launch_bounds__(256) void convmfma_kernel(
    const u16* __restrict__ in, const u16* __restrict__ wbf,
    const float* __restrict__ bias, u16* __restrict__ out)
{
    constexpr int H = 32;
    const int t = threadIdx.x;
    const int base = blockIdx.x * 64;
    const int ochb = blockIdx.y * 32;
    const int m = blockIdx.z;
    const int w = t >> 6, lane = t & 63, q = lane >> 4, l15 = lane & 15;

    const u16* im = in + (size_t)m * NPX * 64;
    const int pxA = base + w * 16 + l15;
    const int yA = pxA / W, xA = pxA - yA * W;
    const bool pxok = (pxA < NPX);

    f32x4 acc[2];
#pragma unroll
    for (int nt = 0; nt < 2; ++nt) acc[nt] = f32x4{0.f, 0.f, 0.f, 0.f};

#pragma unroll
    for (int tap = 0; tap < 9; ++tap) {
        const int dy = tap / 3 - 1, dx = tap % 3 - 1;
        const bool valid = pxok && (yA + dy >= 0) && (yA + dy < H)
                                && (xA + dx >= 0) && (xA + dx < W);
        const u16* ap = im + (size_t)(pxA + dy * W + dx) * 64;
        FragU a0, a1;
        if (valid) {
            a0 = *(const FragU*)(ap + q * 8);
            a1 = *(const FragU*)(ap + 32 + q * 8);
        } else {
#pragma unroll
            for (int jj = 0; jj < 8; ++jj) { a0.u[jj] = 0; a1.u[jj] = 0; }
        }
#pragma unroll
        for (int nt = 0; nt < 2; ++nt) {
            const u16* bp = wbf + tap * 4096 + (ochb + nt * 16 + l15) * 64;
            FragU b0 = *(const FragU*)(bp + q * 8);
            FragU b1 = *(const FragU*)(bp + 32 + q * 8);
            acc[nt] = __builtin_amdgcn_mfma_f32_16x16x32_bf16(a0.v, b0.v, acc[nt], 0, 0, 0);
            acc[nt] = __builtin_amdgcn_mfma_f32_16x16x32_bf16(a1.v, b1.v, acc[nt], 0, 0, 0);
        }
    }

#pragma unroll
    for (int nt = 0; nt < 2; ++nt) {
        const float bb = bias[ochb + nt * 16 + l15];
#pragma unroll
        for (int e = 0; e < 4; ++e) {
            int pxs = base + w * 16 + q * 4 + e;
            if (pxs < NPX)
                out[((size_t)m * NPX + pxs) * 64 + ochb + nt * 16 + l15] =
                    f2bf(fmaxf(acc[nt][e] + bb, 0.f));
        }
    }
}

// ================= MLP (r9/r10-verified single kernel, 195.8us run) ========
__global__ __launch_bounds__(256, 2) void mlp_mfma_kernel(
    const float* __restrict__ lf, const float* __restrict__ flow,
    const u16* __restrict__ feat,   // [bs][2016][64] bf16
    const u16* __restrict__ w1t, const u16* __restrict__ w2t,
    const float* __restrict__ w1, const float* __restrict__ b1,
    const float* __restrict__ b2,
    const float* __restrict__ w3, const float* __restrict__ b3g,
    const float* __restrict__ cw, const float* __restrict__ cbg,
    float* __restrict__ nv_out, float* __restrict__ cf_out)
{
    constexpr int SBS = 72;
    __shared__ __align__(16) float s_vec[7 * 64];
    __shared__ __align__(16) float s_flow[256];
    __shared__ __align__(16) float s_epi[256];
    __shared__ __align__(16) u16 s_base[256 * SBS];

    const int t = threadIdx.x;
    const int blk = blockIdx.x;
    const int bs = blk >> 7;
    const int n0 = (blk & 127) * 8;
    const int b = bs >> 1, s = bs & 1;
    const int w = t >> 6, lane = t & 63, q = lane >> 4, l15 = lane & 15;

    if (t < 64) {
        s_vec[t]       = b1[t];
        s_vec[64 + t]  = b2[t];
        s_vec[128 + t] = w3[t];
        s_vec[192 + t] = cw[t];
        s_vec[256 + t] = w1[t];            // row 0: flow weight
        s_vec[320 + t] = w1[65 * 64 + t];  // row 65: spatial
        s_vec[384 + t] = w1[66 * 64 + t];  // row 66: ang
    }
    {
        int nl = t >> 5, k = t & 31;
        int n = n0 + nl;
        int a = (bs * 32 + (n >> 5)) * 63 + (n & 31) + k;
        s_flow[t] = flow[a];
        s_epi[t]  = lf[a];
    }
    __syncthreads();

    const float b3s = b3g[0];
    const float cbs = cbg[0];

    FragU w1b[2][4];
#pragma unroll
    for (int ks = 0; ks < 2; ++ks)
#pragma unroll
        for (int nt = 0; nt < 4; ++nt)
            w1b[ks][nt] = *(const FragU*)(w1t + (nt * 16 + l15) * 64 + ks * 32 + q * 8);

    float w1r0pl[4], w1r65pl[4], b1pl[4];
#pragma unroll
    for (int nt = 0; nt < 4; ++nt) {
        int j1 = nt * 16 + l15;
        w1r0pl[nt]  = s_vec[256 + j1];
        w1r65pl[nt] = s_vec[320 + j1];
        b1pl[nt]    = s_vec[j1];
    }

#pragma unroll
    for (int mt = 0; mt < 4; ++mt) {
        const int rbase = w * 64 + mt * 16;
        FragU af[2];
        {
            int r = rbase + l15;
            int n = n0 + (r >> 5);
            int pos = (n >> 5) * 63 + (n & 31) + (r & 31);
            const u16* fp = feat + ((size_t)bs * 2016 + pos) * 64;
            af[0] = *(const FragU*)(fp + q * 8);
            af[1] = *(const FragU*)(fp + 32 + q * 8);
        }
        f32x4 flow4 = *(const f32x4*)(s_flow + rbase + q * 4);
#pragma unroll
        for (int nt = 0; nt < 4; ++nt) {
            f32x4 d = {0.f, 0.f, 0.f, 0.f};
            d = __builtin_amdgcn_mfma_f32_16x16x32_bf16(af[0].v, w1b[0][nt].v, d, 0, 0, 0);
            d = __builtin_amdgcn_mfma_f32_16x16x32_bf16(af[1].v, w1b[1][nt].v, d, 0, 0, 0);
#pragma unroll
            for (int e = 0; e < 4; ++e) {
                int r = rbase + q * 4 + e;
                int k = r & 31;
                float val = d[e] + flow4[e] * w1r0pl[nt]
                          + (float)(k - 16) * w1r65pl[nt] + b1pl[nt];
                s_base[r * SBS + nt * 16 + l15] = f2bf(val);
            }
        }
    }
    __syncthreads();

    FragU w2a[4][2];
#pragma unroll
    for (int mt = 0; mt < 4; ++mt)
#pragma unroll
        for (int ks = 0; ks < 2; ++ks)
            w2a[mt][ks] = *(const FragU*)(w2t + (mt * 16 + l15) * 64 + ks * 32 + q * 8);

    float w66pl[2][8];
#pragma unroll
    for (int ks = 0; ks < 2; ++ks)
#pragma unroll
        for (int jj = 0; jj < 8; ++jj)
            w66pl[ks][jj] = s_vec[384 + ks * 32 + q * 8 + jj];

    float b2pl[4][4], w3pl[4][4], cwpl[4][4];
#pragma unroll
    for (int mt = 0; mt < 4; ++mt)
#pragma unroll
        for (int e = 0; e < 4; ++e) {
            b2pl[mt][e] = s_vec[64 + mt * 16 + q * 4 + e];
            w3pl[mt][e] = s_vec[128 + mt * 16 + q * 4 + e];
            cwpl[mt][e] = s_vec[192 + mt * 16 + q * 4 + e];
        }
    float epi_pl[4];
#pragma unroll
    for (int nt = 0; nt < 4; ++nt) epi_pl[nt] = s_epi[w * 64 + nt * 16 + l15];

    for (int v = 0; v < 7; ++v) {
        float ang = (s == 0) ? -(float)(v + 1) : (float)(7 - v);
        f32x4 acc[4][4];
#pragma unroll
        for (int nt = 0; nt < 4; ++nt) {
            FragU bfr[2];
#pragma unroll
            for (int ks = 0; ks < 2; ++ks) {
                const u16x8 raw = *(const u16x8*)(s_base + (w * 64 + nt * 16 + l15) * SBS + ks * 32 + q * 8);
#pragma unroll
                for (int jj = 0; jj < 8; ++jj) {
                    float xv = bf2f(raw[jj]);
                    float hv = fmaxf(xv + ang * w66pl[ks][jj], 0.f);
                    bfr[ks].u[jj] = f2bf(hv);
                }
            }
#pragma unroll
            for (int mt = 0; mt < 4; ++mt) {
                f32x4 d = {0.f, 0.f, 0.f, 0.f};
                d = __builtin_amdgcn_mfma_f32_16x16x32_bf16(w2a[mt][0].v, bfr[0].v, d, 0, 0, 0);
                d = __builtin_amdgcn_mfma_f32_16x16x32_bf16(w2a[mt][1].v, bfr[1].v, d, 0, 0, 0);
                acc[mt][nt] = d;
            }
        }
        float wl[4], cfl[4];
#pragma unroll
        for (int nt = 0; nt < 4; ++nt) {
            float wls = 0.f, cfs = 0.f;
#pragma unroll
            for (int mt = 0; mt < 4; ++mt)
#pragma unroll
                for (int e = 0; e < 4; ++e) {
                    float h2 = fmaxf(acc[mt][nt][e] + b2pl[mt][e], 0.f);
                    wls += h2 * w3pl[mt][e];
                    cfs += h2 * cwpl[mt][e];
                }
            wls += __shfl_xor(wls, 16); wls += __shfl_xor(wls, 32);
            cfs += __shfl_xor(cfs, 16); cfs += __shfl_xor(cfs, 32);
            wl[nt]  = wls + b3s;
            cfl[nt] = cfs;
        }
#pragma unroll
        for (int ni = 0; ni < 2; ++ni) {
            float a0 = wl[ni * 2], a1 = wl[ni * 2 + 1];
            float mx = fmaxf(a0, a1);
#pragma unroll
            for (int msk = 1; msk <= 8; msk <<= 1) mx = fmaxf(mx, __shfl_xor(mx, msk));
            float e0 = __expf(a0 - mx), e1 = __expf(a1 - mx);
            float ssum = e0 + e1;
            float nvp = e0 * epi_pl[ni * 2] + e1 * epi_pl[ni * 2 + 1];
            float cfp = cfl[ni * 2] + cfl[ni * 2 + 1];
#pragma unroll
            for (int msk = 1; msk <= 8; msk <<= 1) {
                ssum += __shfl_xor(ssum, msk);
                nvp  += __shfl_xor(nvp, msk);
                cfp  += __shfl_xor(cfp, msk);
            }
            if (lane == 0) {
                int n = n0 + w * 2 + ni;
                size_t idx = ((size_t)(b * 7 + v) * 2 + s) * 1024 + n;
                nv_out[idx] = nvp / ssum;
                cf_out[idx] = cfp * (1.f / 32.f) + cbs;
            }
        }
    }
}

// ================= refine conv1 + fused conf-combine (r13-verified) ========
__global__ __launch_bounds__(256) void refconv1_kernel(
    const float* __restrict__ nv, const float* __restrict__ cf,
    const float* __restrict__ pl, const float* __restrict__ pr,
    const float* __restrict__ wts, const float* __restrict__ bias,
    u16* __restrict__ out, float* __restrict__ novel)
{
    __shared__ float pn[10][32];
    const int t = threadIdx.x;
    const int og = blockIdx.x, pt = blockIdx.y, m = blockIdx.z;
    const int y0 = pt * 8;

    for (int i = t; i < 320; i += 256) {
        int ri = i >> 5, col = i & 31;
        int gy = y0 - 1 + ri;
        float vv = 0.f;
        if (gy >= 0 && gy < 32) {
            int n = gy * 32 + col;
            size_t i0 = ((size_t)m * 2) * 1024 + n;
            size_t i1 = i0 + 1024;
            float c0 = cf[i0], c1 = cf[i1];
            float mx = fmaxf(c0, c1);
            float e0 = __expf(c0 - mx), e1 = __expf(c1 - mx);
            vv = (e0 * nv[i0] + e1 * nv[i1]) / (e0 + e1);
        }
        pn[ri][col] = vv;
    }
    __syncthreads();

    const int px = y0 * 32 + t;
    const int y = px >> 5, x = px & 31;
    if (og == 0) novel[(size_t)m * 1024 + px] = pn[y - y0 + 1][x];

    float acc[8];
#pragma unroll
    for (int oc = 0; oc < 8; ++oc) acc[oc] = bias[og * 8 + oc];

    {
        float tap[9];
#pragma unroll
        for (int dy = 0; dy < 3; ++dy) {
#pragma unroll
            for (int dx = 0; dx < 3; ++dx) {
                int gx = x + dx - 1;
                tap[dy * 3 + dx] = (gx >= 0 && gx < 32) ? pn[y - y0 + dy][gx] : 0.f;
            }
        }
#pragma unroll
        for (int oc = 0; oc < 8; ++oc) {
            const float* wr = wts + (size_t)(og * 8 + oc) * 27;
#pragma unroll
            for (int j = 0; j < 9; ++j) acc[oc] = fmaf(tap[j], wr[j], acc[oc]);
        }
    }
#pragma unroll
    for (int cin = 1; cin < 3; ++cin) {
        const float* ip = (cin == 1 ? pl : pr) + (size_t)m * 1024;
        float tap[9];
#pragma unroll
        for (int dy = 0; dy < 3; ++dy) {
            int yy = y + dy - 1;
            bool ry = (yy >= 0) && (yy < 32);
#pragma unroll
            for (int dx = 0; dx < 3; ++dx) {
                int xx = x + dx - 1;
                tap[dy * 3 + dx] = (ry && xx >= 0 && xx < 32) ? ip[yy * 32 + xx] : 0.f;
            }
        }
#pragma unroll
        for (int oc = 0; oc < 8; ++oc) {
            const float* wr = wts + (size_t)(og * 8 + oc) * 27 + cin * 9;
#pragma unroll
            for (int j = 0; j < 9; ++j) acc[oc] = fmaf(tap[j], wr[j], acc[oc]);
        }
    }
    u16x8 pk;
#pragma unroll
    for (int oc = 0; oc < 8; ++oc) pk[oc] = f2bf(fmaxf(acc[oc], 0.f));
    *(u16x8*)(out + ((size_t)m * 1024 + px) * 64 + og * 8) = pk;
}

// ================= convlast: 64 -> 1 + bias + residual =====================
__global__ __launch_bounds__(256) void convlast_kernel(
    const u16* __restrict__ in, const float* __restrict__ wts,
    const float* __restrict__ bias, const float* __restrict__ resid,
    float* __restrict__ out)
{
    __shared__ float sw3[576];
    const int t = threadIdx.x;
    for (int i = t; i < 576; i += 256) sw3[i] = wts[i];
    __syncthreads();

    const int tid = blockIdx.x * 256 + t;
    const int m = tid >> 10, p = tid & 1023;
    const int y = p >> 5, x = p & 31;
    float a = bias[0] + resid[tid];
    const u16* im = in + ((size_t)m * 1024 + p) * 64;
#pragma unroll
    for (int dy = 0; dy < 3; ++dy) {
        int yy = y + dy - 1;
        if (yy < 0 || yy >= 32) continue;
#pragma unroll
        for (int dx = 0; dx < 3; ++dx) {
            int xx = x + dx - 1;
            if (xx < 0 || xx >= 32) continue;
            const u16* ip = im + (size_t)((dy - 1) * 32 + (dx - 1)) * 64;
            const int tap = dy * 3 + dx;
#pragma unroll
            for (int cg = 0; cg < 8; ++cg) {
                u16x8 raw = *(const u16x8*)(ip + cg * 8);
#pragma unroll
                for (int e = 0; e < 8; ++e)
                    a = fmaf(bf2f(raw[e]), sw3[(cg * 8 + e) * 9 + tap], a);
            }
        }
    }
    out[tid] = a;
}

// ---------------- launch ----------------
extern "C" void kernel_launch(void* const* d_in, const int* in_sizes, int n_in,
                              void* d_out, int out_size, void* d_ws, size_t ws_size,
                              hipStream_t stream) {
    const float* lf   = (const float*)d_in[0];
    const float* flow = (const float*)d_in[1];
    const float* wp   = (const float*)d_in[2];
    const float* pl   = (const float*)d_in[3];
    const float* pr   = (const float*)d_in[4];
    float* ws = (float*)d_ws;

    conv1feat_kernel<<<dim3(8, 8, 5), 256, 0, stream>>>(
        flow, lf, wp, (const float*)d_in[5], (const float*)d_in[6],
        (u16*)(ws + X1),
        (const float*)d_in[7], (const float*)d_in[9], (const float*)d_in[21],
        (const float*)d_in[11], (const float*)d_in[13],
        (u16*)(ws + WB2F), (u16*)(ws + WB3F), (u16*)(ws + WBV2),
        (u16*)(ws + W1T), (u16*)(ws + W2T));

    convmfma_kernel<63, 2016><<<dim3(32, 2, 4), 256, 0, stream>>>(
        (const u16*)(ws + X1), (const u16*)(ws + WB2F), (const float*)d_in[8],
        (u16*)(ws + X2));
    convmfma_kernel<63, 2016><<<dim3(32, 2, 4), 256, 0, stream>>>(
        (const u16*)(ws + X2), (const u16*)(ws + WB3F), (const float*)d_in[10],
        (u16*)(ws + FEATBF));

    mlp_mfma_kernel<<<512, 256, 0, stream>>>(
        lf, flow, (const u16*)(ws + FEATBF),
        (const u16*)(ws + W1T), (const u16*)(ws + W2T),
        (const float*)d_in[11], (const float*)d_in[12],
        (const float*)d_in[14],
        (const float*)d_in[15], (const float*)d_in[16],
        (const float*)d_in[17], (const float*)d_in[18],
        ws + NVOFF, ws + CFOFF);

    refconv1_kernel<<<dim3(8, 4, 14), 256, 0, stream>>>(
        ws + NVOFF, ws + CFOFF, pl, pr,
        (const float*)d_in[19], (const float*)d_in[20],
        (u16*)(ws + Y1), ws + NOVEL);
    convmfma_kernel<32, 1024><<<dim3(16, 2, 14), 256, 0, stream>>>(
        (const u16*)(ws + Y1), (const u16*)(ws + WBV2), (const float*)d_in[22],
        (u16*)(ws + Y2));
    convlast_kernel<<<56, 256, 0, stream>>>(
        (const u16*)(ws + Y2), (const float*)d_in[23], (const float*)d_in[24],
        ws + NOVEL, (float*)d_out);
}